// Round 4
// baseline (189.311 us; speedup 1.0000x reference)
//
#include <hip/hip_runtime.h>
#include <stdint.h>

#define RES 128
#define NSTEPS 320
#define STEP 0.01f
// alpha > 0.01  <=>  1 - exp(-occ*STEP) > 0.01  <=>  occ > -ln(0.99)/STEP
// exact monotone transform; occ in [0,1) so boundary (1.00503) is unreachable
#define OCC_THRE 1.0050336f

#define SPT 4                 // samples per thread
#define TPR (NSTEPS / SPT)    // 80 threads per ray
#define BLOCK 256

#define NCELLS (RES * RES * RES)      // 2,097,152
#define NWORDS (NCELLS / 32)          // 65,536 words = 256 KB bit grid

typedef float v4f __attribute__((ext_vector_type(4)));   // native vector for nt-store

// Pass 1: threshold the 8 MB occs grid into a 256 KB bit grid (L2-resident).
// Thread w handles cells [w*32, w*32+32) — z-major, so 8 coalesced float4 loads.
__global__ __launch_bounds__(256) void build_bits_kernel(
    const float* __restrict__ occs, uint32_t* __restrict__ bits)
{
    const int w = blockIdx.x * 256 + threadIdx.x;
    const v4f* p = (const v4f*)(occs + (size_t)w * 32);
    uint32_t m = 0;
    #pragma unroll
    for (int q = 0; q < 8; ++q) {
        const v4f v = p[q];
        m |= (v.x > OCC_THRE ? 1u : 0u) << (q * 4 + 0);
        m |= (v.y > OCC_THRE ? 1u : 0u) << (q * 4 + 1);
        m |= (v.z > OCC_THRE ? 1u : 0u) << (q * 4 + 2);
        m |= (v.w > OCC_THRE ? 1u : 0u) << (q * 4 + 3);
    }
    bits[w] = m;
}

__global__ __launch_bounds__(BLOCK) void nerfacc_sampler_kernel(
    const float* __restrict__ origins,     // [N,3]
    const float* __restrict__ dirs,        // [N,3]
    const uint32_t* __restrict__ bits,     // 256 KB occupancy bit grid
    const float* __restrict__ aabb,        // [2,3]
    float* __restrict__ out,               // 7*N*S floats
    int N)
{
    const int T = blockIdx.x * BLOCK + threadIdx.x;
    const int r = T / TPR;
    if (r >= N) return;
    const int j0 = (T - r * TPR) * SPT;

    const float ox = origins[r * 3 + 0];
    const float oy = origins[r * 3 + 1];
    const float oz = origins[r * 3 + 2];
    const float dx = dirs[r * 3 + 0];
    const float dy = dirs[r * 3 + 1];
    const float dz = dirs[r * 3 + 2];
    const float lx = aabb[0], ly = aabb[1], lz = aabb[2];
    const float hx = aabb[3], hy = aabb[4], hz = aabb[5];

    // robust slab intersection (same arithmetic as R1, which matched exactly)
    const float sdx = (fabsf(dx) < 1e-10f) ? 1e-10f : dx;
    const float sdy = (fabsf(dy) < 1e-10f) ? 1e-10f : dy;
    const float sdz = (fabsf(dz) < 1e-10f) ? 1e-10f : dz;
    const float ivx = 1.0f / sdx, ivy = 1.0f / sdy, ivz = 1.0f / sdz;
    const float t0x = (lx - ox) * ivx, t1x = (hx - ox) * ivx;
    const float t0y = (ly - oy) * ivy, t1y = (hy - oy) * ivy;
    const float t0z = (lz - oz) * ivz, t1z = (hz - oz) * ivz;
    float tmin = fmaxf(fmaxf(fminf(t0x, t1x), fminf(t0y, t1y)), fminf(t0z, t1z));
    float tmax = fminf(fminf(fmaxf(t0x, t1x), fmaxf(t0y, t1y)), fmaxf(t0z, t1z));
    tmin = fmaxf(tmin, 0.0f);   // NEAR = 0

    float px[SPT], py[SPT], pz[SPT], ts[SPT], te[SPT], ri[SPT], mm[SPT];
    float uxv[SPT], uyv[SPT], uzv[SPT];
    int bidx[SPT];
    uint32_t wv[SPT];

    // phase 1: addresses (independent)
    #pragma unroll
    for (int i = 0; i < SPT; ++i) {
        const float t_start = tmin + (float)(j0 + i) * STEP;
        const float t_end   = t_start + STEP;
        const float t_mid   = 0.5f * (t_start + t_end);
        const float x = ox + dx * t_mid;
        const float y = oy + dy * t_mid;
        const float z = oz + dz * t_mid;
        const float ux = (x - lx) / (hx - lx);
        const float uy = (y - ly) / (hy - ly);
        const float uz = (z - lz) / (hz - lz);
        int ix = min(max((int)floorf(ux * (float)RES), 0), RES - 1);
        int iy = min(max((int)floorf(uy * (float)RES), 0), RES - 1);
        int iz = min(max((int)floorf(uz * (float)RES), 0), RES - 1);
        bidx[i] = (ix * RES + iy) * RES + iz;       // cell bit index
        uxv[i] = ux; uyv[i] = uy; uzv[i] = uz;
        px[i] = x; py[i] = y; pz[i] = z;
        ts[i] = t_start; te[i] = t_end;
    }
    // phase 2: all gathers in flight together (L2-resident 256 KB array)
    #pragma unroll
    for (int i = 0; i < SPT; ++i) wv[i] = bits[bidx[i] >> 5];

    // phase 3: mask + compaction
    #pragma unroll
    for (int i = 0; i < SPT; ++i) {
        const bool inside = (uxv[i] >= 0.0f) & (uxv[i] < 1.0f) &
                            (uyv[i] >= 0.0f) & (uyv[i] < 1.0f) &
                            (uzv[i] >= 0.0f) & (uzv[i] < 1.0f);
        const bool occ_hit = (wv[i] >> (bidx[i] & 31)) & 1u;
        const bool mask = inside & (te[i] <= tmax) & occ_hit & (tmax > tmin);
        const float m = mask ? 1.0f : 0.0f;
        px[i] *= m; py[i] *= m; pz[i] *= m;
        ts[i] *= m; te[i] *= m;
        ri[i] = mask ? (float)r : -1.0f;
        mm[i] = m;
    }

    // phase 4: vectorized nontemporal stores — dwordx4 nt, coalesced, never re-read
    const size_t NS   = (size_t)N * NSTEPS;
    const size_t base = (size_t)r * NSTEPS + (size_t)j0;

    v4f* pp = (v4f*)(out + base * 3);          // 48 B contiguous per lane
    __builtin_nontemporal_store((v4f){px[0], py[0], pz[0], px[1]}, pp + 0);
    __builtin_nontemporal_store((v4f){py[1], pz[1], px[2], py[2]}, pp + 1);
    __builtin_nontemporal_store((v4f){pz[2], px[3], py[3], pz[3]}, pp + 2);

    __builtin_nontemporal_store((v4f){ts[0], ts[1], ts[2], ts[3]},
                                (v4f*)(out + NS * 3 + base));
    __builtin_nontemporal_store((v4f){te[0], te[1], te[2], te[3]},
                                (v4f*)(out + NS * 4 + base));
    __builtin_nontemporal_store((v4f){ri[0], ri[1], ri[2], ri[3]},
                                (v4f*)(out + NS * 5 + base));
    __builtin_nontemporal_store((v4f){mm[0], mm[1], mm[2], mm[3]},
                                (v4f*)(out + NS * 6 + base));
}

extern "C" void kernel_launch(void* const* d_in, const int* in_sizes, int n_in,
                              void* d_out, int out_size, void* d_ws, size_t ws_size,
                              hipStream_t stream) {
    const float* origins = (const float*)d_in[0];
    const float* dirs    = (const float*)d_in[1];
    const float* occs    = (const float*)d_in[2];
    const float* aabb    = (const float*)d_in[3];
    float* out = (float*)d_out;
    uint32_t* bits = (uint32_t*)d_ws;          // 256 KB of scratch

    const int N = in_sizes[0] / 3;             // 16384

    build_bits_kernel<<<dim3(NWORDS / 256), dim3(256), 0, stream>>>(occs, bits);

    const int total = N * TPR;                 // 1,310,720 threads
    const int grid = (total + BLOCK - 1) / BLOCK;
    nerfacc_sampler_kernel<<<dim3(grid), dim3(BLOCK), 0, stream>>>(
        origins, dirs, bits, aabb, out, N);
}

// Round 5
// 178.724 us; speedup vs baseline: 1.0592x; 1.0592x over previous
//
#include <hip/hip_runtime.h>
#include <stdint.h>

#define RES 128
#define NSTEPS 320
#define STEP 0.01f
// alpha > 0.01  <=>  1 - exp(-occ*STEP) > 0.01  <=>  occ > -ln(0.99)/STEP
// exact monotone transform; occ in [0,1) so the boundary (1.00503) is unreachable
#define OCC_THRE 1.0050336f

#define SPT 4                 // samples per thread
#define TPR (NSTEPS / SPT)    // 80 threads per ray
#define BLOCK 256

typedef float v4f __attribute__((ext_vector_type(4)));

__global__ __launch_bounds__(BLOCK) void nerfacc_sampler_kernel(
    const float* __restrict__ origins,     // [N,3]
    const float* __restrict__ dirs,        // [N,3]
    const float* __restrict__ occs,        // [RES,RES,RES]
    const float* __restrict__ aabb,        // [2,3]
    float* __restrict__ out,               // 7*N*S floats
    int N)
{
    const int T = blockIdx.x * BLOCK + threadIdx.x;
    const int r = T / TPR;
    if (r >= N) return;
    const int j0 = (T - r * TPR) * SPT;

    const float ox = origins[r * 3 + 0];
    const float oy = origins[r * 3 + 1];
    const float oz = origins[r * 3 + 2];
    const float dx = dirs[r * 3 + 0];
    const float dy = dirs[r * 3 + 1];
    const float dz = dirs[r * 3 + 2];
    const float lx = aabb[0], ly = aabb[1], lz = aabb[2];
    const float hx = aabb[3], hy = aabb[4], hz = aabb[5];

    // robust slab intersection (bit-exact vs reference; absmax was 0.0)
    const float sdx = (fabsf(dx) < 1e-10f) ? 1e-10f : dx;
    const float sdy = (fabsf(dy) < 1e-10f) ? 1e-10f : dy;
    const float sdz = (fabsf(dz) < 1e-10f) ? 1e-10f : dz;
    const float ivx = 1.0f / sdx, ivy = 1.0f / sdy, ivz = 1.0f / sdz;
    const float t0x = (lx - ox) * ivx, t1x = (hx - ox) * ivx;
    const float t0y = (ly - oy) * ivy, t1y = (hy - oy) * ivy;
    const float t0z = (lz - oz) * ivz, t1z = (hz - oz) * ivz;
    float tmin = fmaxf(fmaxf(fminf(t0x, t1x), fminf(t0y, t1y)), fminf(t0z, t1z));
    float tmax = fminf(fminf(fmaxf(t0x, t1x), fmaxf(t0y, t1y)), fmaxf(t0z, t1z));
    tmin = fmaxf(tmin, 0.0f);   // NEAR = 0

    float px[SPT], py[SPT], pz[SPT], ts[SPT], te[SPT], ri[SPT], mm[SPT];
    float uxv[SPT], uyv[SPT], uzv[SPT], occv[SPT];
    int gidx[SPT];

    // phase 1: addresses (independent)
    #pragma unroll
    for (int i = 0; i < SPT; ++i) {
        const float t_start = tmin + (float)(j0 + i) * STEP;
        const float t_end   = t_start + STEP;
        const float t_mid   = 0.5f * (t_start + t_end);
        const float x = ox + dx * t_mid;
        const float y = oy + dy * t_mid;
        const float z = oz + dz * t_mid;
        const float ux = (x - lx) / (hx - lx);
        const float uy = (y - ly) / (hy - ly);
        const float uz = (z - lz) / (hz - lz);
        int ix = min(max((int)floorf(ux * (float)RES), 0), RES - 1);
        int iy = min(max((int)floorf(uy * (float)RES), 0), RES - 1);
        int iz = min(max((int)floorf(uz * (float)RES), 0), RES - 1);
        gidx[i] = (ix * RES + iy) * RES + iz;
        uxv[i] = ux; uyv[i] = uy; uzv[i] = uz;
        px[i] = x; py[i] = y; pz[i] = z;
        ts[i] = t_start; te[i] = t_end;
    }
    // phase 2: all gathers in flight together
    #pragma unroll
    for (int i = 0; i < SPT; ++i) occv[i] = occs[gidx[i]];

    // phase 3: mask + compaction
    #pragma unroll
    for (int i = 0; i < SPT; ++i) {
        const bool inside = (uxv[i] >= 0.0f) & (uxv[i] < 1.0f) &
                            (uyv[i] >= 0.0f) & (uyv[i] < 1.0f) &
                            (uzv[i] >= 0.0f) & (uzv[i] < 1.0f);
        const bool mask = inside & (te[i] <= tmax) & (occv[i] > OCC_THRE) & (tmax > tmin);
        const float m = mask ? 1.0f : 0.0f;
        px[i] *= m; py[i] *= m; pz[i] *= m;
        ts[i] *= m; te[i] *= m;
        ri[i] = mask ? (float)r : -1.0f;
        mm[i] = m;
    }

    // phase 4: plain coalesced dwordx4 stores
    const size_t NS   = (size_t)N * NSTEPS;
    const size_t base = (size_t)r * NSTEPS + (size_t)j0;

    v4f* pp = (v4f*)(out + base * 3);          // 48 B contiguous per lane
    pp[0] = (v4f){px[0], py[0], pz[0], px[1]};
    pp[1] = (v4f){py[1], pz[1], px[2], py[2]};
    pp[2] = (v4f){pz[2], px[3], py[3], pz[3]};

    *(v4f*)(out + NS * 3 + base) = (v4f){ts[0], ts[1], ts[2], ts[3]};
    *(v4f*)(out + NS * 4 + base) = (v4f){te[0], te[1], te[2], te[3]};
    *(v4f*)(out + NS * 5 + base) = (v4f){ri[0], ri[1], ri[2], ri[3]};
    *(v4f*)(out + NS * 6 + base) = (v4f){mm[0], mm[1], mm[2], mm[3]};
}

extern "C" void kernel_launch(void* const* d_in, const int* in_sizes, int n_in,
                              void* d_out, int out_size, void* d_ws, size_t ws_size,
                              hipStream_t stream) {
    const float* origins = (const float*)d_in[0];
    const float* dirs    = (const float*)d_in[1];
    const float* occs    = (const float*)d_in[2];
    const float* aabb    = (const float*)d_in[3];
    float* out = (float*)d_out;

    const int N = in_sizes[0] / 3;             // 16384
    const int total = N * TPR;                 // 1,310,720 threads
    const int grid = (total + BLOCK - 1) / BLOCK;

    nerfacc_sampler_kernel<<<dim3(grid), dim3(BLOCK), 0, stream>>>(
        origins, dirs, occs, aabb, out, N);
}